// Round 5
// baseline (2234.038 us; speedup 1.0000x reference)
//
#include <hip/hip_runtime.h>
#include <hip/hip_cooperative_groups.h>
#include <math.h>

namespace cg = cooperative_groups;

typedef __attribute__((ext_vector_type(8))) short short8v;   // 8 bf16 = 4 VGPRs
typedef __attribute__((ext_vector_type(4))) float float4v;   // MFMA acc

constexpr int Bsz = 8, Tn = 16, CINc = 6, Fc = 64, NCc = 10;
constexpr int PIX = 8192;                 // 8*32*32 pixels per timestep
constexpr float BN_EPS = 1e-3f;

// weight-fragment region offsets (in ushort elements)
constexpr int FR_L0X = 0;                 // 2 chunks  (K=54 padded to 64)
constexpr int FR_L0H = 16384;             // 18 chunks (K=576)
constexpr int FR_L1X = 163840;            // 18 chunks
constexpr int FR_L1H = 311296;            // 18 chunks
constexpr int FR_TOTAL = 458752;

constexpr unsigned COOP_LDS = 157696;     // 18*8192 (Bh) + 2*5120 (As dbuf)

__device__ __forceinline__ ushort f2bf(float f) {
    union { float f; unsigned u; } v; v.f = f;
    unsigned r = v.u + 0x7FFFu + ((v.u >> 16) & 1u);   // RNE
    return (ushort)(r >> 16);
}
__device__ __forceinline__ float bf2f(ushort u) {
    union { unsigned u; float f; } v; v.u = ((unsigned)u) << 16; return v.f;
}
__device__ __forceinline__ float hsig(float x) {
    return fminf(fmaxf(0.2f * x + 0.5f, 0.0f), 1.0f);
}

#define GLDS(srcp, dstp) \
    __builtin_amdgcn_global_load_lds((const __attribute__((address_space(1))) void*)(srcp), \
                                     (__attribute__((address_space(3))) void*)(dstp), 16, 0, 0)

// ---------------- prep: x -> bf16 [t][pix][6] ----------------
__global__ __launch_bounds__(256) void prep_x(const float* __restrict__ in,
                                              ushort* __restrict__ xb) {
    int o = blockIdx.x * 256 + threadIdx.x;        // 16*8192*6 = 786432
    if (o >= Tn * PIX * CINc) return;
    int t = o / (PIX * CINc);
    int rem = o - t * (PIX * CINc);
    int pix = rem / CINc, c = rem - pix * CINc;
    int b = pix >> 10, p = pix & 1023;
    xb[o] = f2bf(in[((b * Tn + t) * 1024 + p) * CINc + c]);
}

// ---------------- prep: weights -> grouped B-fragment layout ----------------
// region layout: [kc][nh][j(0..7)][lane(0..63)][e(0..7)]; frag's nt = (j>>1)*4 + nh*2 + (j&1)
// element: k = kc*32 + (lane>>4)*4 + (e&3) + 16*(e>>2); n = nt*16 + (lane&15)
__global__ __launch_bounds__(256) void prep_w(const float* __restrict__ W0x,
                                              const float* __restrict__ W0h,
                                              const float* __restrict__ W1x,
                                              const float* __restrict__ W1h,
                                              ushort* __restrict__ F) {
    int o = blockIdx.x * 256 + threadIdx.x;
    if (o >= FR_TOTAL) return;
    const float* W; int K; int base;
    if (o < FR_L0H)      { W = W0x; K = 54;  base = FR_L0X; }
    else if (o < FR_L1X) { W = W0h; K = 576; base = FR_L0H; }
    else if (o < FR_L1H) { W = W1x; K = 576; base = FR_L1X; }
    else                 { W = W1h; K = 576; base = FR_L1H; }
    int r = o - base;
    int e = r & 7, lane = (r >> 3) & 63, j = (r >> 9) & 7, nh = (r >> 12) & 1, kc = r >> 13;
    int nt = ((j >> 1) << 2) + nh * 2 + (j & 1);
    int k = kc * 32 + ((lane >> 4) * 4) + (e & 3) + 16 * (e >> 2);
    int n = nt * 16 + (lane & 15);
    F[o] = (k < K) ? f2bf(W[k * 256 + n]) : (ushort)0;
}

// ---------------- init ----------------
__global__ __launch_bounds__(256) void init_zero(float* c0, float* c1,
                                                 ushort* h0, ushort* h1,
                                                 ushort* h0b, ushort* h1b, float* out) {
    int i = blockIdx.x * 256 + threadIdx.x;
    if (i < PIX * Fc) { c0[i] = 0.f; c1[i] = 0.f; h0[i] = 0; h1[i] = 0; h0b[i] = 0; h1b[i] = 0; }
    if (i < Bsz * NCc) out[i] = 0.f;
}

// ---------------- batched input-conv GEMM (layer 1): ZXf = conv(x1_t, W1x) + bias ----------------
// grid: 16 t x 128 mtiles x 2 nh = 4096 blocks. Output in FRAGMENT layout:
// ZXf[block(t,bm,nh)][ (j*4+wid)*64+lane ][r]  -> coalesced float4 per lane.
__global__ __launch_bounds__(256) void zx_gemm(
    const ushort* __restrict__ X,
    const ushort* __restrict__ Bf, const float* __restrict__ bias,
    float* __restrict__ ZXf)
{
    __shared__ ushort As[64 * 40];        // 64 rows x 32k (+8 pad) = 80B rows
    __shared__ ushort Bs[2][4096];        // double-buffered 8KB B group

    const int tid = threadIdx.x;
    const int wid = tid >> 6, lane = tid & 63;
    const int bma = blockIdx.x >> 1, nh = blockIdx.x & 1;
    const int t = bma >> 7, bm = bma & 127;
    const int m0 = bm * 64;
    const ushort* __restrict__ Xt = X + t * PIX * Fc;

    const int p_local = tid >> 2, kq = tid & 3;
    const int p_global = m0 + p_local;
    const int img = p_global >> 10, pp = p_global & 1023;
    const int py = pp >> 5, px = pp & 31;

    const int arow_byte = (wid * 16 + (lane & 15)) * 80 + (lane >> 4) * 8;

    auto stageB = [&](int q, int buf) {
        const ushort* g = Bf + ((q * 2 + nh) << 12);
        GLDS(g + (tid << 3),         &Bs[buf][(wid) * 512]);
        GLDS(g + ((256 + tid) << 3), &Bs[buf][(4 + wid) * 512]);
    };
    auto gatherA = [&](int q) -> uint4 {
        uint4 av = make_uint4(0u, 0u, 0u, 0u);
        int tap = q >> 1;
        int c0h = ((q & 1) << 5) + (kq << 3);
        int dy = tap / 3 - 1, dx = tap % 3 - 1;
        int gy = py + dy, gx = px + dx;
        if ((unsigned)gy < 32u && (unsigned)gx < 32u)
            av = *(const uint4*)(Xt + (((img << 10) + gy * 32 + gx) << 6) + c0h);
        return av;
    };

    float4v acc[8];
#pragma unroll
    for (int j = 0; j < 8; ++j)
#pragma unroll
        for (int r = 0; r < 4; ++r) acc[j][r] = 0.f;

    uint4 av = gatherA(0);
    stageB(0, 0);

    for (int q = 0; q < 18; ++q) {
        __syncthreads();
        *(uint4*)((char*)As + p_local * 80 + kq * 16) = av;
        __syncthreads();

        union { struct { uint2 lo, hi; } u; short8v s; } afr;
        afr.u.lo = *(const uint2*)((const char*)As + arow_byte);
        afr.u.hi = *(const uint2*)((const char*)As + arow_byte + 32);

        const ushort* bs = Bs[q & 1];
        union { uint4 u; short8v s; } bf[8];
#pragma unroll
        for (int j = 0; j < 8; ++j)
            bf[j].u = *(const uint4*)(bs + ((j * 64 + lane) << 3));

        if (q + 1 < 18) {
            stageB(q + 1, (q + 1) & 1);
            av = gatherA(q + 1);
        }

#pragma unroll
        for (int j = 0; j < 8; ++j)
            acc[j] = __builtin_amdgcn_mfma_f32_16x16x32_bf16(afr.s, bf[j].s, acc[j], 0, 0, 0);
    }

    // store ZX (+bias) in fragment layout, coalesced float4
    float* outp = ZXf + (((size_t)t * 128 + bm) * 2 + nh) * 8192;
#pragma unroll
    for (int j = 0; j < 8; ++j) {
        const int nt = ((j >> 1) << 2) + nh * 2 + (j & 1);
        const float bb = bias[nt * 16 + (lane & 15)];
        float4 o;
        o.x = acc[j][0] + bb; o.y = acc[j][1] + bb;
        o.z = acc[j][2] + bb; o.w = acc[j][3] + bb;
        *(float4*)(outp + (((j * 4 + wid) * 64 + lane) << 2)) = o;
    }
}

// ---------------- cooperative LSTM layer: 16 steps, grid-sync between ----------------
// grid 256 = 128 mtiles x 2 nh, 1 block/CU. Wh B-chunks preloaded in LDS (144 KB);
// layer0: x-conv (2 chunks) with B in registers, bias in regs; layer1: acc init from ZXf.
__global__ __launch_bounds__(256) void lstm_coop(
    int layer,
    const ushort* __restrict__ Xb, const ushort* __restrict__ BfX,
    const float* __restrict__ ZXf,
    const ushort* __restrict__ BfH, const float* __restrict__ bias,
    float* __restrict__ C, ushort* __restrict__ hbA, ushort* __restrict__ hbB,
    ushort* __restrict__ Seq,
    const float* __restrict__ gamma, const float* __restrict__ beta,
    const float* __restrict__ mean, const float* __restrict__ var)
{
    extern __shared__ ushort lds[];
    ushort* Bh = lds;                  // 18 * 4096 us = 144 KB
    ushort* As = lds + 73728;          // 2 * 2560 us (dbuf, 80B rows)

    const int tid = threadIdx.x;
    const int wid = tid >> 6, lane = tid & 63;
    const int bm = blockIdx.x >> 1, nh = blockIdx.x & 1;
    const int m0 = bm * 64;

    const int p_local = tid >> 2, kq = tid & 3;
    const int p_global = m0 + p_local;
    const int img = p_global >> 10, pp = p_global & 1023;
    const int py = pp >> 5, px = pp & 31;

    const int arow = (wid * 16 + (lane & 15)) * 80 + (lane >> 4) * 8;   // bytes
    const int awr  = p_local * 80 + kq * 16;                            // bytes

    // ---- preload all Wh B-chunks into LDS (once) ----
    for (int q = 0; q < 18; ++q) {
        const ushort* g = BfH + ((q * 2 + nh) << 12);
        GLDS(g + (tid << 3),         Bh + q * 4096 + wid * 512);
        GLDS(g + ((256 + tid) << 3), Bh + q * 4096 + 2048 + wid * 512);
    }

    // ---- layer-0 statics: Wx B-frags in regs, bias, BN consts ----
    uint4 bxr[2][8];
    float bb[8];
    float invc[2], muc[2], betc[2];
    if (layer == 0) {
#pragma unroll
        for (int q = 0; q < 2; ++q)
#pragma unroll
            for (int j = 0; j < 8; ++j)
                bxr[q][j] = *(const uint4*)(BfX + ((q * 2 + nh) << 12) + ((j * 64 + lane) << 3));
#pragma unroll
        for (int j = 0; j < 8; ++j) {
            int nt = ((j >> 1) << 2) + nh * 2 + (j & 1);
            bb[j] = bias[nt * 16 + (lane & 15)];
        }
#pragma unroll
        for (int jj = 0; jj < 2; ++jj) {
            int ch = (nh * 2 + jj) * 16 + (lane & 15);
            invc[jj] = gamma[ch] * rsqrtf(var[ch] + BN_EPS);
            muc[jj] = mean[ch]; betc[jj] = beta[ch];
        }
    }
    __syncthreads();   // drain B preload

    cg::grid_group grid = cg::this_grid();

    for (int t = 0; t < Tn; ++t) {
        const ushort* __restrict__ Hprev = (t & 1) ? hbB : hbA;
        ushort* __restrict__ Hcur = (t & 1) ? hbA : hbB;
        const ushort* __restrict__ Xt = Xb + t * PIX * CINc;

        auto gather_h = [&](int kc) -> uint4 {
            uint4 av = make_uint4(0u, 0u, 0u, 0u);
            int tap = kc >> 1;
            int c0h = ((kc & 1) << 5) + (kq << 3);
            int dy = tap / 3 - 1, dx = tap % 3 - 1;
            int gy = py + dy, gx = px + dx;
            if ((unsigned)gy < 32u && (unsigned)gx < 32u)
                av = *(const uint4*)(Hprev + (((img << 10) + gy * 32 + gx) << 6) + c0h);
            return av;
        };
        auto gather_x = [&](int qq) -> uint4 {
            union { ushort s[8]; uint4 u; } pk;
#pragma unroll
            for (int j = 0; j < 8; ++j) {
                int kg = qq * 32 + kq * 8 + j;
                ushort v = 0;
                if (kg < 54) {
                    int tap = kg / 6, c = kg - tap * 6;
                    int dy = tap / 3 - 1, dx = tap % 3 - 1;
                    int gy = py + dy, gx = px + dx;
                    if ((unsigned)gy < 32u && (unsigned)gx < 32u)
                        v = Xt[((img << 10) + gy * 32 + gx) * 6 + c];
                }
                pk.s[j] = v;
            }
            return pk.u;
        };

        // acc init
        float4v acc[8];
        if (layer == 0) {
#pragma unroll
            for (int j = 0; j < 8; ++j)
#pragma unroll
                for (int r = 0; r < 4; ++r) acc[j][r] = bb[j];
        } else {
            const float* zp = ZXf + (((size_t)t * 128 + bm) * 2 + nh) * 8192;
#pragma unroll
            for (int j = 0; j < 8; ++j)
                acc[j] = *(const float4v*)(zp + (((j * 4 + wid) * 64 + lane) << 2));
        }

        // pipeline prologue: chunk 0 staged, chunk 1 prefetched
        uint4 a0 = (layer == 0) ? gather_x(0) : gather_h(0);
        *(uint4*)((char*)As + awr) = a0;
        uint4 av_n = (layer == 0) ? gather_x(1) : gather_h(1);
        __syncthreads();

        // peeled x-chunks (layer 0 only): B from registers, static index
        if (layer == 0) {
#pragma unroll
            for (int qq = 0; qq < 2; ++qq) {
                union { struct { uint2 lo, hi; } u; short8v s; } afr;
                const char* ab = (const char*)As + (qq & 1) * 5120 + arow;
                afr.u.lo = *(const uint2*)(ab);
                afr.u.hi = *(const uint2*)(ab + 32);

                *(uint4*)((char*)As + ((qq + 1) & 1) * 5120 + awr) = av_n;
                av_n = gather_h(qq);           // next chunks: h0, h1

                union { uint4 u; short8v s; } bfr;
#pragma unroll
                for (int j = 0; j < 8; ++j) {
                    bfr.u = bxr[qq][j];
                    acc[j] = __builtin_amdgcn_mfma_f32_16x16x32_bf16(afr.s, bfr.s, acc[j], 0, 0, 0);
                }
                __syncthreads();
            }
        }

        // h-chunks: B from preloaded LDS. Parity (kc+XC)&1 == kc&1 since XC even.
        for (int kc = 0; kc < 18; ++kc) {
            union { struct { uint2 lo, hi; } u; short8v s; } afr;
            const char* ab = (const char*)As + (kc & 1) * 5120 + arow;
            afr.u.lo = *(const uint2*)(ab);
            afr.u.hi = *(const uint2*)(ab + 32);

            if (kc + 1 < 18) {
                *(uint4*)((char*)As + ((kc + 1) & 1) * 5120 + awr) = av_n;
                if (kc + 2 < 18) av_n = gather_h(kc + 2);
            }

            const ushort* bs = Bh + kc * 4096;
            union { uint4 u; short8v s; } bfr[8];
#pragma unroll
            for (int j = 0; j < 8; ++j)
                bfr[j].u = *(const uint4*)(bs + ((j * 64 + lane) << 3));
#pragma unroll
            for (int j = 0; j < 8; ++j)
                acc[j] = __builtin_amdgcn_mfma_f32_16x16x32_bf16(afr.s, bfr[j].s, acc[j], 0, 0, 0);
            __syncthreads();
        }

        // fused gate epilogue: j=0,1 -> i; 2,3 -> f; 4,5 -> g; 6,7 -> o
#pragma unroll
        for (int jj = 0; jj < 2; ++jj) {
            const int ch = (nh * 2 + jj) * 16 + (lane & 15);
#pragma unroll
            for (int r = 0; r < 4; ++r) {
                const int p = m0 + wid * 16 + (lane >> 4) * 4 + r;
                const int o = p * 64 + ch;
                float zi = acc[0 + jj][r];
                float zf = acc[2 + jj][r];
                float zg = acc[4 + jj][r];
                float zo = acc[6 + jj][r];
                float cv = hsig(zf) * C[o] + hsig(zi) * tanhf(zg);
                C[o] = cv;
                float h = hsig(zo) * tanhf(cv);
                Hcur[o] = f2bf(h);
                Seq[(size_t)t * (PIX * Fc) + o] =
                    (layer == 0) ? f2bf((h - muc[jj]) * invc[jj] + betc[jj]) : f2bf(h);
            }
        }

        __threadfence();
        grid.sync();
    }
}

// ---------------- pool over all t: BN1(h1) @ denseW -> softmax -> mean ----------------
__global__ __launch_bounds__(256) void pool_all(
    const ushort* __restrict__ H1seq, const float* __restrict__ dW,
    const float* __restrict__ dB,
    const float* __restrict__ gamma, const float* __restrict__ beta,
    const float* __restrict__ mean, const float* __restrict__ var,
    float* __restrict__ out)
{
    __shared__ float accs[NCc];
    int gid = blockIdx.x * 256 + threadIdx.x;   // 512 blocks x 256 = 131072
    int pix = gid & 8191;
    int b = pix >> 10;
    if (threadIdx.x < NCc) accs[threadIdx.x] = 0.f;
    __syncthreads();

    float logit[NCc];
#pragma unroll
    for (int c = 0; c < NCc; ++c) logit[c] = dB[c];
    const ushort* hp = H1seq + (size_t)gid * Fc;
    for (int f0 = 0; f0 < Fc; f0 += 8) {
        uint4 hv = *(const uint4*)(hp + f0);
        union { uint4 u; ushort s[8]; } hu; hu.u = hv;
#pragma unroll
        for (int j = 0; j < 8; ++j) {
            int f = f0 + j;
            float inv = gamma[f] * rsqrtf(var[f] + BN_EPS);
            float v = (bf2f(hu.s[j]) - mean[f]) * inv + beta[f];
#pragma unroll
            for (int c = 0; c < NCc; ++c) logit[c] += v * dW[f * NCc + c];
        }
    }
    float mx = logit[0];
#pragma unroll
    for (int c = 1; c < NCc; ++c) mx = fmaxf(mx, logit[c]);
    float p[NCc]; float s = 0.f;
#pragma unroll
    for (int c = 0; c < NCc; ++c) { p[c] = expf(logit[c] - mx); s += p[c]; }
    float invs = 1.f / s;
#pragma unroll
    for (int c = 0; c < NCc; ++c) atomicAdd(&accs[c], p[c] * invs);
    __syncthreads();
    if (threadIdx.x < NCc)
        atomicAdd(&out[b * NCc + threadIdx.x], accs[threadIdx.x] * (1.0f / 16384.0f));
}

extern "C" void kernel_launch(void* const* d_in, const int* in_sizes, int n_in,
                              void* d_out, int out_size, void* d_ws, size_t ws_size,
                              hipStream_t stream) {
    const float* in    = (const float*)d_in[0];
    const float* l0Wx  = (const float*)d_in[1];
    const float* l0Wh  = (const float*)d_in[2];
    const float* l0b   = (const float*)d_in[3];
    const float* l0g   = (const float*)d_in[4];
    const float* l0be  = (const float*)d_in[5];
    const float* l0m   = (const float*)d_in[6];
    const float* l0v   = (const float*)d_in[7];
    const float* l1Wx  = (const float*)d_in[8];
    const float* l1Wh  = (const float*)d_in[9];
    const float* l1b   = (const float*)d_in[10];
    const float* l1g   = (const float*)d_in[11];
    const float* l1be  = (const float*)d_in[12];
    const float* l1m   = (const float*)d_in[13];
    const float* l1v   = (const float*)d_in[14];
    const float* dW    = (const float*)d_in[15];
    const float* dB    = (const float*)d_in[16];
    float* out = (float*)d_out;

    float* ws   = (float*)d_ws;
    float* c0   = ws;                        // 524,288 f
    float* c1   = c0 + 524288;
    float* zx   = c1 + 524288;               // 33,554,432 f (128 MB), layer-1 ZX fragments
    ushort* us  = (ushort*)(zx + 33554432);
    ushort* h0p0 = us;                       // h ping-pong buffers (bf16)
    ushort* h0p1 = h0p0 + 524288;
    ushort* h1p0 = h0p1 + 524288;
    ushort* h1p1 = h1p0 + 524288;
    ushort* xb  = h1p1 + 524288;             // 786,432 us
    ushort* x1  = xb + 786432;               // 16*524,288 us (BN'd layer-0 output)
    ushort* h1s = x1 + 8388608;              // 16*524,288 us (layer-1 h sequence)
    ushort* wf  = h1s + 8388608;             // 458,752 us

    prep_x<<<3072, 256, 0, stream>>>(in, xb);
    prep_w<<<1792, 256, 0, stream>>>(l0Wx, l0Wh, l1Wx, l1Wh, wf);
    init_zero<<<2048, 256, 0, stream>>>(c0, c1, h0p0, h1p0, h0p1, h1p1, out);

    hipFuncSetAttribute((const void*)lstm_coop,
                        hipFuncAttributeMaxDynamicSharedMemorySize, COOP_LDS);

    // ---- layer 0 (cooperative, x-conv in-kernel) ----
    {
        int layer = 0;
        const ushort* bfx = wf + FR_L0X;
        const ushort* bfh = wf + FR_L0H;
        const float* zxf = zx;   // unused
        void* args[] = { &layer, &xb, &bfx, &zxf, &bfh, &l0b,
                         &c0, &h0p0, &h0p1, &x1,
                         &l0g, &l0be, &l0m, &l0v };
        hipLaunchCooperativeKernel((const void*)lstm_coop, dim3(256), dim3(256),
                                   args, COOP_LDS, stream);
    }
    // ---- layer 1 input conv (batched, fragment-layout output) ----
    zx_gemm<<<4096, 256, 0, stream>>>(x1, wf + FR_L1X, l1b, zx);
    // ---- layer 1 (cooperative) ----
    {
        int layer = 1;
        const ushort* bfx = wf + FR_L1X;   // unused
        const ushort* bfh = wf + FR_L1H;
        const float* zxf = zx;
        void* args[] = { &layer, &xb, &bfx, &zxf, &bfh, &l1b,
                         &c1, &h1p0, &h1p1, &h1s,
                         &l1g, &l1be, &l1m, &l1v };
        hipLaunchCooperativeKernel((const void*)lstm_coop, dim3(256), dim3(256),
                                   args, COOP_LDS, stream);
    }
    pool_all<<<512, 256, 0, stream>>>(h1s, dW, dB, l1g, l1be, l1m, l1v, out);
}

// Round 6
// 448.161 us; speedup vs baseline: 4.9849x; 4.9849x over previous
//
#include <hip/hip_runtime.h>
#include <math.h>

typedef __attribute__((ext_vector_type(8))) short short8v;   // 8 bf16 = 4 VGPRs
typedef __attribute__((ext_vector_type(4))) float float4v;   // MFMA acc

constexpr int Bsz = 8, Tn = 16, CINc = 6, Fc = 64, NCc = 10;
constexpr int PIX = 8192;                 // 8*32*32 pixels per timestep
constexpr float BN_EPS = 1e-3f;

// weight-fragment region offsets (in ushort elements)
constexpr int FR_L0X = 0;                 // 2 chunks  (K=54 padded to 64)
constexpr int FR_L0H = 16384;             // 18 chunks (K=576)
constexpr int FR_L1X = 163840;            // 18 chunks
constexpr int FR_L1H = 311296;            // 18 chunks
constexpr int FR_TOTAL = 458752;

__device__ __forceinline__ ushort f2bf(float f) {
    union { float f; unsigned u; } v; v.f = f;
    unsigned r = v.u + 0x7FFFu + ((v.u >> 16) & 1u);   // RNE
    return (ushort)(r >> 16);
}
__device__ __forceinline__ float bf2f(ushort u) {
    union { unsigned u; float f; } v; v.u = ((unsigned)u) << 16; return v.f;
}
__device__ __forceinline__ float hsig(float x) {
    return fminf(fmaxf(0.2f * x + 0.5f, 0.0f), 1.0f);
}

#define GLDS(srcp, dstp) \
    __builtin_amdgcn_global_load_lds((const __attribute__((address_space(1))) void*)(srcp), \
                                     (__attribute__((address_space(3))) void*)(dstp), 16, 0, 0)

// ---------------- prep: x -> bf16 [t][pix][6] ----------------
__global__ __launch_bounds__(256) void prep_x(const float* __restrict__ in,
                                              ushort* __restrict__ xb) {
    int o = blockIdx.x * 256 + threadIdx.x;        // 16*8192*6 = 786432
    if (o >= Tn * PIX * CINc) return;
    int t = o / (PIX * CINc);
    int rem = o - t * (PIX * CINc);
    int pix = rem / CINc, c = rem - pix * CINc;
    int b = pix >> 10, p = pix & 1023;
    xb[o] = f2bf(in[((b * Tn + t) * 1024 + p) * CINc + c]);
}

// ---------------- prep: weights -> grouped B-fragment layout ----------------
// region layout: [kc][nh][j(0..7)][lane(0..63)][e(0..7)]; frag's nt = (j>>1)*4 + nh*2 + (j&1)
// element: k = kc*32 + (lane>>4)*4 + (e&3) + 16*(e>>2); n = nt*16 + (lane&15)
__global__ __launch_bounds__(256) void prep_w(const float* __restrict__ W0x,
                                              const float* __restrict__ W0h,
                                              const float* __restrict__ W1x,
                                              const float* __restrict__ W1h,
                                              ushort* __restrict__ F) {
    int o = blockIdx.x * 256 + threadIdx.x;
    if (o >= FR_TOTAL) return;
    const float* W; int K; int base;
    if (o < FR_L0H)      { W = W0x; K = 54;  base = FR_L0X; }
    else if (o < FR_L1X) { W = W0h; K = 576; base = FR_L0H; }
    else if (o < FR_L1H) { W = W1x; K = 576; base = FR_L1X; }
    else                 { W = W1h; K = 576; base = FR_L1H; }
    int r = o - base;
    int e = r & 7, lane = (r >> 3) & 63, j = (r >> 9) & 7, nh = (r >> 12) & 1, kc = r >> 13;
    int nt = ((j >> 1) << 2) + nh * 2 + (j & 1);
    int k = kc * 32 + ((lane >> 4) * 4) + (e & 3) + 16 * (e >> 2);
    int n = nt * 16 + (lane & 15);
    F[o] = (k < K) ? f2bf(W[k * 256 + n]) : (ushort)0;
}

// ---------------- init ----------------
__global__ __launch_bounds__(256) void init_zero(float* c0, float* c1,
                                                 ushort* h0, ushort* h1,
                                                 ushort* h0b, ushort* h1b, float* out) {
    int i = blockIdx.x * 256 + threadIdx.x;
    if (i < PIX * Fc) { c0[i] = 0.f; c1[i] = 0.f; h0[i] = 0; h1[i] = 0; h0b[i] = 0; h1b[i] = 0; }
    if (i < Bsz * NCc) out[i] = 0.f;
}

// ---------------- dual-layer pipelined step ----------------
// Blocks 0..255:   layer-0 step t      (skip if t >= 16): z = conv(x_t,W0x)+conv(h0,W0h)+b0
// Blocks 256..511: layer-1 step t-1    (skip if t == 0):  z = conv(x1[t-1],W1x)+conv(h1,W1h)+b1
// Each block: 64 pixels x 128 gate-paired channels (nh half); register-local gate math.
__global__ __launch_bounds__(256) void step_dual(
    int t,
    const ushort* __restrict__ Xb,
    const ushort* __restrict__ Bf0X, const ushort* __restrict__ Bf0H,
    const float* __restrict__ b0,
    float* __restrict__ C0, const ushort* __restrict__ H0prev, ushort* __restrict__ H0cur,
    ushort* __restrict__ X1s,
    const float* __restrict__ g0, const float* __restrict__ be0,
    const float* __restrict__ mn0, const float* __restrict__ v0,
    const ushort* __restrict__ Bf1X, const ushort* __restrict__ Bf1H,
    const float* __restrict__ b1,
    float* __restrict__ C1, const ushort* __restrict__ H1prev, ushort* __restrict__ H1cur,
    ushort* __restrict__ H1s)
{
    const int layer = blockIdx.x >> 8;
    if (layer == 0) { if (t >= Tn) return; }
    else            { if (t == 0)  return; }

    __shared__ ushort As[64 * 40];        // 64 rows x 32k (+8 pad) = 80B rows
    __shared__ ushort Bs[2][4096];        // double-buffered 8KB B group

    const int tid = threadIdx.x;
    const int wid = tid >> 6, lane = tid & 63;
    const int bid = blockIdx.x & 255;
    const int bm = bid >> 1, nh = bid & 1;
    const int m0 = bm * 64;

    const int p_local = tid >> 2, kq = tid & 3;
    const int p_global = m0 + p_local;
    const int img = p_global >> 10, pp = p_global & 1023;
    const int py = pp >> 5, px = pp & 31;

    const int arow = (wid * 16 + (lane & 15)) * 80 + (lane >> 4) * 8;   // bytes
    const int awr  = p_local * 80 + kq * 16;                            // bytes

    // per-layer bindings
    const int t1 = t - 1;
    const ushort* __restrict__ Xt    = Xb + t * PIX * CINc;                  // layer 0
    const ushort* __restrict__ X1t1  = X1s + (size_t)t1 * (PIX * Fc);        // layer 1
    const ushort* __restrict__ Hprev = (layer == 0) ? H0prev : H1prev;
    ushort* __restrict__ Hcur        = (layer == 0) ? H0cur : H1cur;
    float* __restrict__ C            = (layer == 0) ? C0 : C1;
    const float* __restrict__ bias   = (layer == 0) ? b0 : b1;
    ushort* __restrict__ Seq         = (layer == 0) ? (X1s + (size_t)t * (PIX * Fc))
                                                    : (H1s + (size_t)t1 * (PIX * Fc));
    const int TOT = (layer == 0) ? 20 : 36;      // L0: 2 x-chunks + 18 h; L1: 18 + 18
    const int XC  = (layer == 0) ? 2 : 18;

    auto bptr = [&](int q) -> const ushort* {
        if (layer == 0)
            return (q < 2)  ? Bf0X + ((q * 2 + nh) << 12)
                            : Bf0H + (((q - 2) * 2 + nh) << 12);
        else
            return (q < 18) ? Bf1X + ((q * 2 + nh) << 12)
                            : Bf1H + (((q - 18) * 2 + nh) << 12);
    };
    auto stageB = [&](int q, int buf) {
        const ushort* g = bptr(q);
        GLDS(g + (tid << 3),         &Bs[buf][(wid) * 512]);
        GLDS(g + ((256 + tid) << 3), &Bs[buf][(4 + wid) * 512]);
    };
    auto gather64 = [&](const ushort* __restrict__ P, int kc) -> uint4 {
        uint4 av = make_uint4(0u, 0u, 0u, 0u);
        int tap = kc >> 1;
        int c0h = ((kc & 1) << 5) + (kq << 3);
        int dy = tap / 3 - 1, dx = tap % 3 - 1;
        int gy = py + dy, gx = px + dx;
        if ((unsigned)gy < 32u && (unsigned)gx < 32u)
            av = *(const uint4*)(P + (((img << 10) + gy * 32 + gx) << 6) + c0h);
        return av;
    };
    auto gatherA = [&](int q) -> uint4 {
        if (layer == 0) {
            if (q < 2) {                         // x path, Ch=6, K=54 pad 64
                union { ushort s[8]; uint4 u; } pk;
#pragma unroll
                for (int j = 0; j < 8; ++j) {
                    int kg = q * 32 + kq * 8 + j;
                    ushort v = 0;
                    if (kg < 54) {
                        int tap = kg / 6, c = kg - tap * 6;
                        int dy = tap / 3 - 1, dx = tap % 3 - 1;
                        int gy = py + dy, gx = px + dx;
                        if ((unsigned)gy < 32u && (unsigned)gx < 32u)
                            v = Xt[((img << 10) + gy * 32 + gx) * 6 + c];
                    }
                    pk.s[j] = v;
                }
                return pk.u;
            }
            return gather64(Hprev, q - 2);
        } else {
            return (q < 18) ? gather64(X1t1, q) : gather64(Hprev, q - 18);
        }
    };

    // acc init = bias (z = x-conv + h-conv + bias accumulated in-register)
    float4v acc[8];
#pragma unroll
    for (int j = 0; j < 8; ++j) {
        const int nt = ((j >> 1) << 2) + nh * 2 + (j & 1);
        const float bb = bias[nt * 16 + (lane & 15)];
#pragma unroll
        for (int r = 0; r < 4; ++r) acc[j][r] = bb;
    }

    uint4 av = gatherA(0);
    stageB(0, 0);

    for (int q = 0; q < TOT; ++q) {
        __syncthreads();    // drains glds of B(q); prior iter's LDS reads done
        *(uint4*)((char*)As + awr) = av;
        __syncthreads();    // publish As

        union { struct { uint2 lo, hi; } u; short8v s; } afr;
        afr.u.lo = *(const uint2*)((const char*)As + arow);
        afr.u.hi = *(const uint2*)((const char*)As + arow + 32);

        const ushort* bs = Bs[q & 1];
        union { uint4 u; short8v s; } bfr[8];
#pragma unroll
        for (int j = 0; j < 8; ++j)
            bfr[j].u = *(const uint4*)(bs + ((j * 64 + lane) << 3));

        if (q + 1 < TOT) {                      // prefetch during MFMA region
            stageB(q + 1, (q + 1) & 1);
            av = gatherA(q + 1);
        }

#pragma unroll
        for (int j = 0; j < 8; ++j)
            acc[j] = __builtin_amdgcn_mfma_f32_16x16x32_bf16(afr.s, bfr[j].s, acc[j], 0, 0, 0);
    }

    // fused gate epilogue: j=0,1 -> i; 2,3 -> f; 4,5 -> g; 6,7 -> o
#pragma unroll
    for (int jj = 0; jj < 2; ++jj) {
        const int ch = (nh * 2 + jj) * 16 + (lane & 15);   // h-channel 0..63
        float inv = 0.f, mu = 0.f, bet = 0.f;
        if (layer == 0) {
            inv = g0[ch] * rsqrtf(v0[ch] + BN_EPS);
            mu = mn0[ch]; bet = be0[ch];
        }
#pragma unroll
        for (int r = 0; r < 4; ++r) {
            const int p = m0 + wid * 16 + (lane >> 4) * 4 + r;
            const int o = p * 64 + ch;
            float zi = acc[0 + jj][r];
            float zf = acc[2 + jj][r];
            float zg = acc[4 + jj][r];
            float zo = acc[6 + jj][r];
            float cv = hsig(zf) * C[o] + hsig(zi) * tanhf(zg);
            C[o] = cv;
            float h = hsig(zo) * tanhf(cv);
            Hcur[o] = f2bf(h);
            Seq[o] = (layer == 0) ? f2bf((h - mu) * inv + bet) : f2bf(h);
        }
    }
}

// ---------------- pool over all t: BN1(h1) @ denseW -> softmax -> mean ----------------
__global__ __launch_bounds__(256) void pool_all(
    const ushort* __restrict__ H1seq, const float* __restrict__ dW,
    const float* __restrict__ dB,
    const float* __restrict__ gamma, const float* __restrict__ beta,
    const float* __restrict__ mean, const float* __restrict__ var,
    float* __restrict__ out)
{
    __shared__ float accs[NCc];
    int gid = blockIdx.x * 256 + threadIdx.x;   // 512 blocks x 256 = 131072
    int pix = gid & 8191;
    int b = pix >> 10;
    if (threadIdx.x < NCc) accs[threadIdx.x] = 0.f;
    __syncthreads();

    float logit[NCc];
#pragma unroll
    for (int c = 0; c < NCc; ++c) logit[c] = dB[c];
    const ushort* hp = H1seq + (size_t)gid * Fc;
    for (int f0 = 0; f0 < Fc; f0 += 8) {
        uint4 hv = *(const uint4*)(hp + f0);
        union { uint4 u; ushort s[8]; } hu; hu.u = hv;
#pragma unroll
        for (int j = 0; j < 8; ++j) {
            int f = f0 + j;
            float inv = gamma[f] * rsqrtf(var[f] + BN_EPS);
            float v = (bf2f(hu.s[j]) - mean[f]) * inv + beta[f];
#pragma unroll
            for (int c = 0; c < NCc; ++c) logit[c] += v * dW[f * NCc + c];
        }
    }
    float mx = logit[0];
#pragma unroll
    for (int c = 1; c < NCc; ++c) mx = fmaxf(mx, logit[c]);
    float p[NCc]; float s = 0.f;
#pragma unroll
    for (int c = 0; c < NCc; ++c) { p[c] = expf(logit[c] - mx); s += p[c]; }
    float invs = 1.f / s;
#pragma unroll
    for (int c = 0; c < NCc; ++c) atomicAdd(&accs[c], p[c] * invs);
    __syncthreads();
    if (threadIdx.x < NCc)
        atomicAdd(&out[b * NCc + threadIdx.x], accs[threadIdx.x] * (1.0f / 16384.0f));
}

extern "C" void kernel_launch(void* const* d_in, const int* in_sizes, int n_in,
                              void* d_out, int out_size, void* d_ws, size_t ws_size,
                              hipStream_t stream) {
    const float* in    = (const float*)d_in[0];
    const float* l0Wx  = (const float*)d_in[1];
    const float* l0Wh  = (const float*)d_in[2];
    const float* l0b   = (const float*)d_in[3];
    const float* l0g   = (const float*)d_in[4];
    const float* l0be  = (const float*)d_in[5];
    const float* l0m   = (const float*)d_in[6];
    const float* l0v   = (const float*)d_in[7];
    const float* l1Wx  = (const float*)d_in[8];
    const float* l1Wh  = (const float*)d_in[9];
    const float* l1b   = (const float*)d_in[10];
    const float* l1g   = (const float*)d_in[11];
    const float* l1be  = (const float*)d_in[12];
    const float* l1m   = (const float*)d_in[13];
    const float* l1v   = (const float*)d_in[14];
    const float* dW    = (const float*)d_in[15];
    const float* dB    = (const float*)d_in[16];
    float* out = (float*)d_out;

    float* ws   = (float*)d_ws;
    float* c0   = ws;                        // 524,288 f
    float* c1   = c0 + 524288;
    ushort* us  = (ushort*)(c1 + 524288);
    ushort* h0p0 = us;                       // h ping-pong buffers (bf16)
    ushort* h0p1 = h0p0 + 524288;
    ushort* h1p0 = h0p1 + 524288;
    ushort* h1p1 = h1p0 + 524288;
    ushort* xb  = h1p1 + 524288;             // 786,432 us
    ushort* x1  = xb + 786432;               // 16*524,288 us (BN'd layer-0 output)
    ushort* h1s = x1 + 8388608;              // 16*524,288 us (layer-1 h sequence)
    ushort* wf  = h1s + 8388608;             // 458,752 us

    ushort* h0p[2] = { h0p0, h0p1 };
    ushort* h1p[2] = { h1p0, h1p1 };

    prep_x<<<3072, 256, 0, stream>>>(in, xb);
    prep_w<<<1792, 256, 0, stream>>>(l0Wx, l0Wh, l1Wx, l1Wh, wf);
    init_zero<<<2048, 256, 0, stream>>>(c0, c1, h0p0, h1p0, h0p1, h1p1, out);

    // wavefront pipeline: slot t runs layer-0 step t and layer-1 step t-1
    for (int t = 0; t <= Tn; ++t) {
        int t1c = (t > 0) ? (t - 1) : 0;
        step_dual<<<512, 256, 0, stream>>>(
            t, xb,
            wf + FR_L0X, wf + FR_L0H, l0b,
            c0, h0p[t & 1], h0p[(t + 1) & 1], x1,
            l0g, l0be, l0m, l0v,
            wf + FR_L1X, wf + FR_L1H, l1b,
            c1, h1p[t1c & 1], h1p[(t1c + 1) & 1], h1s);
    }
    pool_all<<<512, 256, 0, stream>>>(h1s, dW, dB, l1g, l1be, l1m, l1v, out);
}